// Round 1
// baseline (993.648 us; speedup 1.0000x reference)
//
#include <hip/hip_runtime.h>
#include <stdint.h>

typedef unsigned short u16;
typedef __attribute__((ext_vector_type(8))) short short8;
typedef __attribute__((ext_vector_type(4))) float f32x4;

typedef __attribute__((address_space(1))) const unsigned int as1_uint;
typedef __attribute__((address_space(3))) unsigned int as3_uint;

#define MFMA16(a, b, c) __builtin_amdgcn_mfma_f32_16x16x32_bf16((a), (b), (c), 0, 0, 0)

__device__ __forceinline__ u16 f2bf(float f) {
  unsigned u = __float_as_uint(f);
  u += 0x7fffu + ((u >> 16) & 1u);
  return (u16)(u >> 16);
}

// ---------------- fp32 -> bf16 convert (vectorized) ----------------
__global__ void cvt_kernel(const float* __restrict__ in, u16* __restrict__ out, int n4) {
  int i = blockIdx.x * blockDim.x + threadIdx.x;
  int stride = gridDim.x * blockDim.x;
  for (; i < n4; i += stride) {
    float4 v = ((const float4*)in)[i];
    ushort4 o;
    o.x = f2bf(v.x); o.y = f2bf(v.y); o.z = f2bf(v.z); o.w = f2bf(v.w);
    ((ushort4*)out)[i] = o;
  }
}

// ---------------- GEMM: C = A(M,K) * B(N,K)^T, m97 structure ----------------
// MODE 0: +bias -> bf16, layout (b, h, s, d)   (Q)
// MODE 1: same                                  (K)
// MODE 2: +bias -> bf16, layout (b, h, d, s)   (V transposed)
// MODE 3: +bias -> fp32, layout (row, col)     (output projection)
template <int MODE>
__global__ __launch_bounds__(256, 2) void gemm_bt(
    const u16* __restrict__ A, const u16* __restrict__ Bm,
    const float* __restrict__ bias, void* __restrict__ outp) {
  constexpr int K = 1024;
  constexpr int NK = K / 32;
  __shared__ u16 Asm[2][128][32];
  __shared__ u16 Bsm[2][128][32];
  const int tid = threadIdx.x;
  const int w = tid >> 6, l = tid & 63;
  const int tileM = blockIdx.x * 128, tileN = blockIdx.y * 128;
  const int lr = l >> 2;          // row within 16-row staging group
  const int lk = (l & 3) * 8;     // k-element offset of this lane's 16B

  f32x4 zero = {0.f, 0.f, 0.f, 0.f};
  f32x4 acc[4][4];
#pragma unroll
  for (int i = 0; i < 4; ++i)
#pragma unroll
    for (int j = 0; j < 4; ++j) acc[i][j] = zero;

  const int wm = (w >> 1) * 64, wn = (w & 1) * 64;
  const int fr = l & 15, fk = (l >> 4) * 8;

  auto stage = [&](int buf, int k0) {
#pragma unroll
    for (int j = 0; j < 2; ++j) {
      const int r0 = (j * 4 + w) * 16;
      const u16* srcA = A + (size_t)(tileM + r0 + lr) * K + (k0 + lk);
      __builtin_amdgcn_global_load_lds((as1_uint*)srcA, (as3_uint*)&Asm[buf][r0][0], 16, 0, 0);
      const u16* srcB = Bm + (size_t)(tileN + r0 + lr) * K + (k0 + lk);
      __builtin_amdgcn_global_load_lds((as1_uint*)srcB, (as3_uint*)&Bsm[buf][r0][0], 16, 0, 0);
    }
  };

  stage(0, 0);
  for (int ks = 0; ks < NK; ++ks) {
    const int buf = ks & 1;
    __syncthreads();
    if (ks + 1 < NK) stage(buf ^ 1, (ks + 1) * 32);
    short8 af[4], bfr[4];
#pragma unroll
    for (int i = 0; i < 4; ++i) af[i] = *(const short8*)&Asm[buf][wm + i * 16 + fr][fk];
#pragma unroll
    for (int j = 0; j < 4; ++j) bfr[j] = *(const short8*)&Bsm[buf][wn + j * 16 + fr][fk];
#pragma unroll
    for (int i = 0; i < 4; ++i)
#pragma unroll
      for (int j = 0; j < 4; ++j) acc[i][j] = MFMA16(af[i], bfr[j], acc[i][j]);
  }

  const int fg = (l >> 4) * 4;
#pragma unroll
  for (int i = 0; i < 4; ++i)
#pragma unroll
    for (int j = 0; j < 4; ++j) {
      const int row0 = tileM + wm + i * 16 + fg;
      const int col = tileN + wn + j * 16 + fr;
      const float bval = bias[col];
      if (MODE == 3) {
        float* out = (float*)outp;
#pragma unroll
        for (int r = 0; r < 4; ++r)
          out[(size_t)(row0 + r) * 1024 + col] = acc[i][j][r] + bval;
      } else if (MODE == 2) {
        u16* out = (u16*)outp;
        const int b = row0 >> 11, s = row0 & 2047;
        const int hh = col >> 6, d = col & 63;
        ushort4 v;
        v.x = f2bf(acc[i][j][0] + bval);
        v.y = f2bf(acc[i][j][1] + bval);
        v.z = f2bf(acc[i][j][2] + bval);
        v.w = f2bf(acc[i][j][3] + bval);
        *(ushort4*)&out[((size_t)(b * 16 + hh) * 64 + d) * 2048 + s] = v;
      } else {
        u16* out = (u16*)outp;
#pragma unroll
        for (int r = 0; r < 4; ++r) {
          const int row = row0 + r;
          const int b = row >> 11, s = row & 2047;
          const int hh = col >> 6, d = col & 63;
          out[((size_t)(b * 16 + hh) * 2048 + s) * 64 + d] = f2bf(acc[i][j][r] + bval);
        }
      }
    }
}

// ---------------- attention: scores -> softmax -> probs write -> PV ----------------
// grid (S/16, NH, B), 256 threads (4 waves). Full 16x2048 fp32 score tile in LDS.
__global__ __launch_bounds__(256, 1) void attn_kernel(
    const u16* __restrict__ Qb, const u16* __restrict__ Kb,
    const u16* __restrict__ VTb, const int* __restrict__ amask,
    const float* __restrict__ biasc, float* __restrict__ probs,
    u16* __restrict__ ctx) {
  constexpr int SP = 2052;  // padded row stride (floats) -> conflict-free-ish
  __shared__ float sc[16 * SP];          // 131,328 B
  __shared__ float ctxred[4][16][64];    // 16,384 B
  __shared__ float invb[16];
  const int tid = threadIdx.x;
  const int w = tid >> 6, l = tid & 63;
  const int b = blockIdx.z, h = blockIdx.y;
  const int q0 = blockIdx.x * 16;
  const size_t bh = (size_t)(b * 16 + h);
  const u16* Qp = Qb + (bh * 2048 + q0) * 64;
  const u16* Kp = Kb + bh * 2048 * 64;
  const u16* Vp = VTb + bh * 64 * 2048;
  const float bc = biasc[h];
  const int fr = l & 15, fk = (l >> 4) * 8, fg = (l >> 4) * 4;

  f32x4 zero = {0.f, 0.f, 0.f, 0.f};

  // Q fragments (16 rows x 64 d), kept in registers for the whole kernel
  short8 aq0 = *(const short8*)&Qp[fr * 64 + fk];
  short8 aq1 = *(const short8*)&Qp[fr * 64 + 32 + fk];

  // ---- scores: wave w covers k-columns [w*512, (w+1)*512) ----
  const int* mrow = amask + b * 2048;
  for (int t = 0; t < 32; ++t) {
    const int kc = w * 512 + t * 16;
    const u16* kp = Kp + (size_t)kc * 64;
    short8 b0 = *(const short8*)&kp[fr * 64 + fk];
    short8 b1 = *(const short8*)&kp[fr * 64 + 32 + fk];
    f32x4 acc = zero;
    acc = MFMA16(aq0, b0, acc);
    acc = MFMA16(aq1, b1, acc);
    const int col = kc + fr;
    const int mk = mrow[col];
#pragma unroll
    for (int r = 0; r < 4; ++r) {
      float v = acc[r] * 0.125f - bc;
      if (mk == 0) v = -1e9f;
      sc[(fg + r) * SP + col] = v;
    }
  }
  __syncthreads();

  // ---- softmax: wave w owns rows w*4 .. w*4+3; exact (max-subtract) fp32 ----
  for (int rr = 0; rr < 4; ++rr) {
    const int row = w * 4 + rr;
    float* sr = &sc[row * SP];
    float m = -3.0e38f;
#pragma unroll
    for (int i = 0; i < 8; ++i) {
      float4 v = *(const float4*)&sr[i * 256 + l * 4];
      m = fmaxf(m, fmaxf(fmaxf(v.x, v.y), fmaxf(v.z, v.w)));
    }
#pragma unroll
    for (int off = 32; off > 0; off >>= 1) m = fmaxf(m, __shfl_xor(m, off, 64));
    float s = 0.f;
#pragma unroll
    for (int i = 0; i < 8; ++i) {
      float4 v = *(const float4*)&sr[i * 256 + l * 4];
      v.x = __expf(v.x - m); v.y = __expf(v.y - m);
      v.z = __expf(v.z - m); v.w = __expf(v.w - m);
      *(float4*)&sr[i * 256 + l * 4] = v;   // keep unnormalized e in LDS for PV
      s += (v.x + v.y) + (v.z + v.w);
    }
#pragma unroll
    for (int off = 32; off > 0; off >>= 1) s += __shfl_xor(s, off, 64);
    const float inv = 1.0f / s;
    if (l == 0) invb[row] = inv;
    float* pr = probs + (bh * 2048 + q0 + row) * 2048;
#pragma unroll
    for (int i = 0; i < 8; ++i) {
      float4 v = *(const float4*)&sr[i * 256 + l * 4];
      v.x *= inv; v.y *= inv; v.z *= inv; v.w *= inv;
      *(float4*)&pr[i * 256 + l * 4] = v;   // coalesced 1KB/wave-instr
    }
  }
  __syncthreads();

  // ---- PV: wave w contracts its k-range; V^T layout gives contiguous B-frags ----
  f32x4 acc4[4];
#pragma unroll
  for (int jd = 0; jd < 4; ++jd) acc4[jd] = zero;
  for (int t = 0; t < 16; ++t) {
    const int kb = w * 512 + t * 32;
    float4 e0 = *(const float4*)&sc[fr * SP + kb + fk];
    float4 e1 = *(const float4*)&sc[fr * SP + kb + fk + 4];
    short8 ap;
    ap[0] = (short)f2bf(e0.x); ap[1] = (short)f2bf(e0.y);
    ap[2] = (short)f2bf(e0.z); ap[3] = (short)f2bf(e0.w);
    ap[4] = (short)f2bf(e1.x); ap[5] = (short)f2bf(e1.y);
    ap[6] = (short)f2bf(e1.z); ap[7] = (short)f2bf(e1.w);
#pragma unroll
    for (int jd = 0; jd < 4; ++jd) {
      const u16* vp = Vp + (size_t)(jd * 16 + fr) * 2048 + kb + fk;
      short8 bv = *(const short8*)vp;
      acc4[jd] = MFMA16(ap, bv, acc4[jd]);
    }
  }
#pragma unroll
  for (int jd = 0; jd < 4; ++jd)
#pragma unroll
    for (int r = 0; r < 4; ++r) ctxred[w][fg + r][jd * 16 + fr] = acc4[jd][r];
  __syncthreads();
#pragma unroll
  for (int e = 0; e < 4; ++e) {
    const int idx = tid + e * 256;
    const int row = idx >> 6, d = idx & 63;
    float v = ctxred[0][row][d] + ctxred[1][row][d] + ctxred[2][row][d] + ctxred[3][row][d];
    v *= invb[row];
    ctx[(size_t)(b * 2048 + q0 + row) * 1024 + h * 64 + d] = f2bf(v);
  }
}

extern "C" void kernel_launch(void* const* d_in, const int* in_sizes, int n_in,
                              void* d_out, int out_size, void* d_ws, size_t ws_size,
                              hipStream_t stream) {
  const float* hs = (const float*)d_in[0];
  const int* amask = (const int*)d_in[1];
  const float* Wq = (const float*)d_in[2];
  const float* bq = (const float*)d_in[3];
  const float* Wk = (const float*)d_in[4];
  const float* bk = (const float*)d_in[5];
  const float* Wv = (const float*)d_in[6];
  const float* bv = (const float*)d_in[7];
  const float* Wo = (const float*)d_in[8];
  const float* bo = (const float*)d_in[9];
  const float* biasc = (const float*)d_in[10];
  float* out = (float*)d_out;
  float* probs = out + (size_t)4 * 2048 * 1024;

  char* ws = (char*)d_ws;
  u16* hsb = (u16*)(ws + 0);           // 16 MiB   bf16 hidden (8192 x 1024)
  u16* wqb = (u16*)(ws + 16777216);    // 2 MiB
  u16* wkb = (u16*)(ws + 18874368);
  u16* wvb = (u16*)(ws + 20971520);
  u16* wob = (u16*)(ws + 23068672);
  u16* Qb  = (u16*)(ws + 25165824);    // 16 MiB   (b,h,s,d)
  u16* Kb  = (u16*)(ws + 41943040);    // 16 MiB   (b,h,s,d)
  u16* VTb = (u16*)(ws + 58720256);    // 16 MiB   (b,h,d,s)
  u16* ctx = (u16*)(ws + 75497472);    // 16 MiB   (b*s, h*d)

  cvt_kernel<<<2048, 256, 0, stream>>>(hs, hsb, 8388608 / 4);
  cvt_kernel<<<1024, 256, 0, stream>>>(Wq, wqb, 1048576 / 4);
  cvt_kernel<<<1024, 256, 0, stream>>>(Wk, wkb, 1048576 / 4);
  cvt_kernel<<<1024, 256, 0, stream>>>(Wv, wvb, 1048576 / 4);
  cvt_kernel<<<1024, 256, 0, stream>>>(Wo, wob, 1048576 / 4);

  dim3 gg(64, 8);
  gemm_bt<0><<<gg, 256, 0, stream>>>(hsb, wqb, bq, (void*)Qb);
  gemm_bt<1><<<gg, 256, 0, stream>>>(hsb, wkb, bk, (void*)Kb);
  gemm_bt<2><<<gg, 256, 0, stream>>>(hsb, wvb, bv, (void*)VTb);

  attn_kernel<<<dim3(128, 16, 4), 256, 0, stream>>>(Qb, Kb, VTb, amask, biasc, probs, ctx);

  gemm_bt<3><<<gg, 256, 0, stream>>>(ctx, wob, bo, d_out);
}